// Round 1
// baseline (214.152 us; speedup 1.0000x reference)
//
#include <hip/hip_runtime.h>
#include <math.h>

#define Bn 4
#define Tn 4096
#define Cn 1024
#define Hn 64

typedef __attribute__((ext_vector_type(8))) short short8;
typedef __attribute__((ext_vector_type(4))) float floatx4;

__device__ __forceinline__ unsigned short f2bf(float f) {
  union { float f; unsigned u; } v; v.f = f;
  unsigned r = v.u + 0x7FFFu + ((v.u >> 16) & 1u);  // RNE
  return (unsigned short)(r >> 16);
}

// ---------------------------------------------------------------------------
// QKV projection: Qb = (x@Wq)*0.125 (bf16), Kb = x@Wk (bf16), Vt = (x@Wv)^T
// Vt layout: [B][H][T] so attention PV B-frags are contiguous b128 reads.
// grid = 256 blocks (64 rows each), 256 threads (4 waves, wave owns 16 rows).
// ---------------------------------------------------------------------------
__global__ __launch_bounds__(256) void qkv_proj_kernel(
    const float* __restrict__ x, const float* __restrict__ Wq,
    const float* __restrict__ Wk, const float* __restrict__ Wv,
    unsigned short* __restrict__ Qb, unsigned short* __restrict__ Kb,
    unsigned short* __restrict__ Vt)
{
  // xs[row][c] : 64 rows x 32 c (bf16), pad 40 (16B-aligned rows, bank-safe)
  // wt[m*64+h][c] : W^T chunks for 3 mats
  __shared__ __align__(16) unsigned short xs[64][40];
  __shared__ __align__(16) unsigned short wt[192][40];
  const int tid  = threadIdx.x;
  const int wv   = tid >> 6;         // wave 0..3
  const int lane = tid & 63;
  const int col  = lane & 15;
  const int quad = lane >> 4;
  const int r0   = blockIdx.x << 6;  // first of 64 rows

  const int xrow = tid >> 3, xc4 = tid & 7;  // x staging: f4 per (row, c4)
  const int wh = tid & 63, wcg = tid >> 6;   // W staging: h column, c-group

  float4 xr0, xr1;
  float wr0[8], wr1[8], wr2[8];

  // prefetch chunk 0
  {
    const float* xp = x + (size_t)(r0 + xrow) * Cn + xc4 * 4;
    xr0 = *(const float4*)(xp);
    xr1 = *(const float4*)(xp + 32 * Cn);
#pragma unroll
    for (int i = 0; i < 8; ++i) {
      int cidx = (wcg * 8 + i) * Hn + wh;
      wr0[i] = Wq[cidx]; wr1[i] = Wk[cidx]; wr2[i] = Wv[cidx];
    }
  }

  floatx4 acc[3][4];
#pragma unroll
  for (int m = 0; m < 3; ++m)
#pragma unroll
    for (int nt = 0; nt < 4; ++nt) {
      acc[m][nt][0] = 0.f; acc[m][nt][1] = 0.f;
      acc[m][nt][2] = 0.f; acc[m][nt][3] = 0.f;
    }

  for (int ch = 0; ch < 32; ++ch) {
    // ---- stage prefetched regs to LDS (fp32 -> bf16) ----
    {
      ushort4 a;
      a.x = f2bf(xr0.x); a.y = f2bf(xr0.y); a.z = f2bf(xr0.z); a.w = f2bf(xr0.w);
      *(ushort4*)&xs[xrow][xc4 * 4] = a;
      a.x = f2bf(xr1.x); a.y = f2bf(xr1.y); a.z = f2bf(xr1.z); a.w = f2bf(xr1.w);
      *(ushort4*)&xs[xrow + 32][xc4 * 4] = a;

      uint4 u;
      u.x = (unsigned)f2bf(wr0[0]) | ((unsigned)f2bf(wr0[1]) << 16);
      u.y = (unsigned)f2bf(wr0[2]) | ((unsigned)f2bf(wr0[3]) << 16);
      u.z = (unsigned)f2bf(wr0[4]) | ((unsigned)f2bf(wr0[5]) << 16);
      u.w = (unsigned)f2bf(wr0[6]) | ((unsigned)f2bf(wr0[7]) << 16);
      *(uint4*)&wt[wh][wcg * 8] = u;
      u.x = (unsigned)f2bf(wr1[0]) | ((unsigned)f2bf(wr1[1]) << 16);
      u.y = (unsigned)f2bf(wr1[2]) | ((unsigned)f2bf(wr1[3]) << 16);
      u.z = (unsigned)f2bf(wr1[4]) | ((unsigned)f2bf(wr1[5]) << 16);
      u.w = (unsigned)f2bf(wr1[6]) | ((unsigned)f2bf(wr1[7]) << 16);
      *(uint4*)&wt[64 + wh][wcg * 8] = u;
      u.x = (unsigned)f2bf(wr2[0]) | ((unsigned)f2bf(wr2[1]) << 16);
      u.y = (unsigned)f2bf(wr2[2]) | ((unsigned)f2bf(wr2[3]) << 16);
      u.z = (unsigned)f2bf(wr2[4]) | ((unsigned)f2bf(wr2[5]) << 16);
      u.w = (unsigned)f2bf(wr2[6]) | ((unsigned)f2bf(wr2[7]) << 16);
      *(uint4*)&wt[128 + wh][wcg * 8] = u;
    }
    __syncthreads();

    // ---- prefetch next chunk (overlaps MFMA phase) ----
    if (ch < 31) {
      int c0 = (ch + 1) * 32;
      const float* xp = x + (size_t)(r0 + xrow) * Cn + c0 + xc4 * 4;
      xr0 = *(const float4*)(xp);
      xr1 = *(const float4*)(xp + 32 * Cn);
#pragma unroll
      for (int i = 0; i < 8; ++i) {
        int cidx = (c0 + wcg * 8 + i) * Hn + wh;
        wr0[i] = Wq[cidx]; wr1[i] = Wk[cidx]; wr2[i] = Wv[cidx];
      }
    }

    // ---- MFMA: A = x rows (m=lane&15, k=quad*8+j), B = W^T (n=lane&15) ----
    short8 af = *(const short8*)&xs[wv * 16 + col][quad * 8];
#pragma unroll
    for (int m = 0; m < 3; ++m) {
#pragma unroll
      for (int nt = 0; nt < 4; ++nt) {
        short8 bfm = *(const short8*)&wt[m * 64 + nt * 16 + col][quad * 8];
        acc[m][nt] = __builtin_amdgcn_mfma_f32_16x16x32_bf16(af, bfm, acc[m][nt], 0, 0, 0);
      }
    }
    __syncthreads();
  }

  // C/D layout: col = lane&15, row = quad*4 + reg  [verified m89/m91]
#pragma unroll
  for (int nt = 0; nt < 4; ++nt) {
#pragma unroll
    for (int r = 0; r < 4; ++r) {
      int rr = r0 + wv * 16 + quad * 4 + r;
      int h  = nt * 16 + col;
      Qb[(size_t)rr * Hn + h] = f2bf(acc[0][nt][r] * 0.125f);  // fold H^-0.5
      Kb[(size_t)rr * Hn + h] = f2bf(acc[1][nt][r]);
      int bb = rr >> 12, t = rr & 4095;
      Vt[(size_t)((bb << 6) + h) * Tn + t] = f2bf(acc[2][nt][r]);
    }
  }
}

// ---------------------------------------------------------------------------
// Flash attention, causal. grid = B*64 blocks; block = q-tile of 64 rows,
// 4 waves, wave owns 16 q rows (full softmax rows in-wave).
// ---------------------------------------------------------------------------
__global__ __launch_bounds__(256) void attn_kernel(
    const unsigned short* __restrict__ Qb, const unsigned short* __restrict__ Kb,
    const unsigned short* __restrict__ Vt, float* __restrict__ out)
{
  __shared__ __align__(16) unsigned short Qs[64][72];
  __shared__ __align__(16) unsigned short Ks[64][72];
  __shared__ __align__(16) unsigned short Vs[64][72];  // Vs[h][s] (pre-transposed)
  __shared__ __align__(16) unsigned short Ps[64][72];  // P round-trip C->A layout

  const int tid  = threadIdx.x;
  const int wv   = tid >> 6;
  const int lane = tid & 63;
  const int col  = lane & 15;
  const int quad = lane >> 4;
  const int b  = blockIdx.x >> 6;
  const int qt = blockIdx.x & 63;

  const int srow = tid >> 3, sc8 = tid & 7;  // staging: uint4 per (row, c8)

  // stage Q tile (bf16, 64x64)
  const uint4* Qg = (const uint4*)(Qb + (size_t)(b * Tn + qt * 64) * Hn);
  *(uint4*)&Qs[srow][sc8 * 8]      = Qg[srow * 8 + sc8];
  *(uint4*)&Qs[srow + 32][sc8 * 8] = Qg[(srow + 32) * 8 + sc8];

  const uint4* Kg = (const uint4*)(Kb + (size_t)b * Tn * Hn);
  const uint4* Vg = (const uint4*)(Vt + (size_t)b * Hn * Tn);

  uint4 kr0, kr1, vr0, vr1;
  auto loadKV = [&](int kbl) {
    kr0 = Kg[(kbl * 64 + srow) * 8 + sc8];
    kr1 = Kg[(kbl * 64 + srow + 32) * 8 + sc8];
    vr0 = Vg[srow * (Tn / 8) + kbl * 8 + sc8];
    vr1 = Vg[(srow + 32) * (Tn / 8) + kbl * 8 + sc8];
  };
  loadKV(0);
  __syncthreads();

  // Q A-frags, hoisted: A[m=lane&15][k=quad*8+j (+32)]
  short8 qf0 = *(const short8*)&Qs[wv * 16 + col][quad * 8];
  short8 qf1 = *(const short8*)&Qs[wv * 16 + col][32 + quad * 8];

  floatx4 o[4];
#pragma unroll
  for (int ht = 0; ht < 4; ++ht) { o[ht][0]=0.f; o[ht][1]=0.f; o[ht][2]=0.f; o[ht][3]=0.f; }
  float m_i[4], l_i[4];
#pragma unroll
  for (int r = 0; r < 4; ++r) { m_i[r] = -INFINITY; l_i[r] = 0.f; }

  for (int kb = 0; kb <= qt; ++kb) {
    // write prefetched K/V tile to LDS (safe: previous iter ended with barrier)
    *(uint4*)&Ks[srow][sc8 * 8]      = kr0;
    *(uint4*)&Ks[srow + 32][sc8 * 8] = kr1;
    *(uint4*)&Vs[srow][sc8 * 8]      = vr0;
    *(uint4*)&Vs[srow + 32][sc8 * 8] = vr1;
    __syncthreads();
    if (kb < qt) loadKV(kb + 1);  // overlaps compute

    // S = Q K^T  (16q x 64k per wave); B-frag: n=key=lane&15, k=h=quad*8+j
    floatx4 s[4];
#pragma unroll
    for (int kt = 0; kt < 4; ++kt) {
      short8 kf0 = *(const short8*)&Ks[kt * 16 + col][quad * 8];
      short8 kf1 = *(const short8*)&Ks[kt * 16 + col][32 + quad * 8];
      floatx4 c; c[0]=0.f; c[1]=0.f; c[2]=0.f; c[3]=0.f;
      c = __builtin_amdgcn_mfma_f32_16x16x32_bf16(qf0, kf0, c, 0, 0, 0);
      c = __builtin_amdgcn_mfma_f32_16x16x32_bf16(qf1, kf1, c, 0, 0, 0);
      s[kt] = c;
    }

    if (kb == qt) {  // diagonal tile: mask key > query
#pragma unroll
      for (int kt = 0; kt < 4; ++kt)
#pragma unroll
        for (int r = 0; r < 4; ++r)
          if (kt * 16 + col > wv * 16 + quad * 4 + r) s[kt][r] = -INFINITY;
    }

    // online softmax; row = quad*4+r, 16 cols live in the quad's 16 lanes
    float mx[4], al[4], rs[4];
#pragma unroll
    for (int r = 0; r < 4; ++r)
      mx[r] = fmaxf(fmaxf(s[0][r], s[1][r]), fmaxf(s[2][r], s[3][r]));
#pragma unroll
    for (int off = 1; off < 16; off <<= 1)
#pragma unroll
      for (int r = 0; r < 4; ++r)
        mx[r] = fmaxf(mx[r], __shfl_xor(mx[r], off, 64));
#pragma unroll
    for (int r = 0; r < 4; ++r) {
      float mn = fmaxf(m_i[r], mx[r]);
      al[r] = __expf(m_i[r] - mn);
      m_i[r] = mn;
    }
#pragma unroll
    for (int kt = 0; kt < 4; ++kt)
#pragma unroll
      for (int r = 0; r < 4; ++r)
        s[kt][r] = __expf(s[kt][r] - m_i[r]);
#pragma unroll
    for (int r = 0; r < 4; ++r)
      rs[r] = (s[0][r] + s[1][r]) + (s[2][r] + s[3][r]);
#pragma unroll
    for (int off = 1; off < 16; off <<= 1)
#pragma unroll
      for (int r = 0; r < 4; ++r)
        rs[r] += __shfl_xor(rs[r], off, 64);
#pragma unroll
    for (int r = 0; r < 4; ++r)
      l_i[r] = l_i[r] * al[r] + rs[r];

    // P: C-layout regs -> LDS (own rows only; same-wave RAW, no barrier needed)
#pragma unroll
    for (int kt = 0; kt < 4; ++kt)
#pragma unroll
      for (int r = 0; r < 4; ++r)
        Ps[wv * 16 + quad * 4 + r][kt * 16 + col] = f2bf(s[kt][r]);

    // rescale O by alpha
#pragma unroll
    for (int ht = 0; ht < 4; ++ht)
#pragma unroll
      for (int r = 0; r < 4; ++r)
        o[ht][r] *= al[r];

    // O += P V ; A-frag P[m=q=lane&15][k=s], B-frag Vs[n=h=lane&15][k=s]
    short8 pf0 = *(const short8*)&Ps[wv * 16 + col][quad * 8];
    short8 pf1 = *(const short8*)&Ps[wv * 16 + col][32 + quad * 8];
#pragma unroll
    for (int ht = 0; ht < 4; ++ht) {
      short8 vf0 = *(const short8*)&Vs[ht * 16 + col][quad * 8];
      short8 vf1 = *(const short8*)&Vs[ht * 16 + col][32 + quad * 8];
      o[ht] = __builtin_amdgcn_mfma_f32_16x16x32_bf16(pf0, vf0, o[ht], 0, 0, 0);
      o[ht] = __builtin_amdgcn_mfma_f32_16x16x32_bf16(pf1, vf1, o[ht], 0, 0, 0);
    }
    __syncthreads();  // all waves done reading Ks/Vs before next staging write
  }

#pragma unroll
  for (int r = 0; r < 4; ++r) {
    float inv = 1.f / l_i[r];
    size_t base = (size_t)(b * Tn + qt * 64 + wv * 16 + quad * 4 + r) * Hn;
#pragma unroll
    for (int ht = 0; ht < 4; ++ht)
      out[base + ht * 16 + col] = o[ht][r] * inv;
  }
}

extern "C" void kernel_launch(void* const* d_in, const int* in_sizes, int n_in,
                              void* d_out, int out_size, void* d_ws, size_t ws_size,
                              hipStream_t stream) {
  const float* x  = (const float*)d_in[0];
  const float* Wq = (const float*)d_in[1];
  const float* Wk = (const float*)d_in[2];
  const float* Wv = (const float*)d_in[3];
  float* out = (float*)d_out;

  unsigned short* Qb = (unsigned short*)d_ws;              // [B*T][64] bf16, pre-scaled
  unsigned short* Kb = Qb + (size_t)Bn * Tn * Hn;          // [B*T][64] bf16
  unsigned short* Vt = Kb + (size_t)Bn * Tn * Hn;          // [B][64][T] bf16 (transposed)

  qkv_proj_kernel<<<dim3(256), dim3(256), 0, stream>>>(x, Wq, Wk, Wv, Qb, Kb, Vt);
  attn_kernel<<<dim3(Bn * 64), dim3(256), 0, stream>>>(Qb, Kb, Vt, out);
}